// Round 7
// baseline (162.527 us; speedup 1.0000x reference)
//
#include <hip/hip_runtime.h>
#include <hip/hip_bf16.h>

#define MARGIN 0.0625f

// Problem sizes
#define P 4096            // queries (64*64)
#define M 100000          // means
#define MT 6400           // mean tiles of 16 (padded: 6400*16 = 102400)
#define MTA (MT + 1)      // +1 slack tile so the prefetch never reads junk
#define MPAD (MTA * 16)   // 102416 mean slots filled by prep
#define S 200             // mean segments (nn grid.x)
#define TPS (MT / S)      // 32 tiles per segment
#define QG 4              // query groups (nn grid.y); 64 qtiles each
#define QTW 16            // qtiles per wave (4 waves * 16 * 16 = 1024 q/block)

using short8 = __attribute__((ext_vector_type(8))) short;
using f4     = __attribute__((ext_vector_type(4))) float;

// ws layout (bytes):
//   Abuf : 256 qt * 64 lanes * 16 B = 262,144            @ 0
//   Bbuf : 6401 mt * 64 lanes * 16 B = 6,554,624          @ 262,144
//   qq   : 4096 * 4 = 16,384                              @ 6,816,768
//   part : 200 * 4096 * 4 = 3,276,800                     @ 6,833,152
#define WS_A_OFF    0
#define WS_B_OFF    262144
#define WS_QQ_OFF   6816768
#define WS_PART_OFF 6833152

__device__ inline unsigned short bf16_rn(float x) {
    unsigned u = __float_as_uint(x);
    return (unsigned short)((u + 0x7FFFu + ((u >> 16) & 1u)) >> 16);
}
__device__ inline float bf16_tof(unsigned short h) {
    return __uint_as_float(((unsigned)h) << 16);
}

// ---------------------------------------------------------------------------
// Kernel 1: build MFMA fragments.
//  Mean j -> B k-slots: [vxh vxl vxh | vyh vyl vyh | vzh vzl vzh | mm1 mm2 mm3 | 0..]
//  Query p -> A k-slots: [uxh uxh uxl | uyh uyh uyl | uzh uzh uzl | 1 1 1 | 0..]
//  (u = -2q, 2-way splits; mm 3-way split)  =>  sum_k A*B = mm - 2 q.m
//  Layout (16x16x32): elem of row/col (lane&15), k = (lane>>4)*8 + j.
// ---------------------------------------------------------------------------
__global__ __launch_bounds__(256) void prep_kernel(
    const float* __restrict__ outputs, const float* __restrict__ c2ws,
    const float* __restrict__ scales,  const float* __restrict__ means,
    short8* __restrict__ Abuf, short8* __restrict__ Bbuf,
    float* __restrict__ qq, float* __restrict__ out)
{
    int idx = blockIdx.x * 256 + threadIdx.x;
    if (idx == 0) out[0] = 0.0f;   // reduce atomicAdds later (stream-ordered)

    if (idx < MPAD) {              // ---- mean side ----
        short kv[32];
#pragma unroll
        for (int i = 0; i < 32; ++i) kv[i] = 0;
        if (idx < M) {
            float x = means[3 * idx], y = means[3 * idx + 1], z = means[3 * idx + 2];
            float mm = fmaf(x, x, fmaf(y, y, z * z));
            unsigned short xh = bf16_rn(x), yh = bf16_rn(y), zh = bf16_rn(z);
            unsigned short xl = bf16_rn(x - bf16_tof(xh));
            unsigned short yl = bf16_rn(y - bf16_tof(yh));
            unsigned short zl = bf16_rn(z - bf16_tof(zh));
            unsigned short m1 = bf16_rn(mm);
            float r1 = mm - bf16_tof(m1);
            unsigned short m2 = bf16_rn(r1);
            unsigned short m3 = bf16_rn(r1 - bf16_tof(m2));
            kv[0] = (short)xh; kv[1] = (short)xl; kv[2] = (short)xh;
            kv[3] = (short)yh; kv[4] = (short)yl; kv[5] = (short)yh;
            kv[6] = (short)zh; kv[7] = (short)zl; kv[8] = (short)zh;
            kv[9] = (short)m1; kv[10] = (short)m2; kv[11] = (short)m3;
        } else {
            kv[9] = (short)bf16_rn(1e30f);   // pad mean: e = 1e30, never wins min
        }
        int mt = idx >> 4, n = idx & 15;
#pragma unroll
        for (int quad = 0; quad < 4; ++quad) {
            short8 c;
#pragma unroll
            for (int j = 0; j < 8; ++j) c[j] = kv[quad * 8 + j];
            Bbuf[mt * 64 + quad * 16 + n] = c;
        }
    }

    int qidx = idx - MPAD;         // ---- query side ----
    if (qidx >= 0 && qidx < P) {
        int b = qidx >> 6;
        float s  = scales[b];
        float o0 = outputs[3 * qidx + 0];
        float o1 = outputs[3 * qidx + 1];
        float o2 = outputs[3 * qidx + 2];
        const float* cw = c2ws + b * 16;
        float q0 = fmaf(s, fmaf(cw[0],  o0, fmaf(cw[1],  o1, cw[2]  * o2)), cw[3]);
        float q1 = fmaf(s, fmaf(cw[4],  o0, fmaf(cw[5],  o1, cw[6]  * o2)), cw[7]);
        float q2 = fmaf(s, fmaf(cw[8],  o0, fmaf(cw[9],  o1, cw[10] * o2)), cw[11]);
        qq[qidx] = fmaf(q0, q0, fmaf(q1, q1, q2 * q2));
        float ux = -2.0f * q0, uy = -2.0f * q1, uz = -2.0f * q2;
        unsigned short xh = bf16_rn(ux), yh = bf16_rn(uy), zh = bf16_rn(uz);
        unsigned short xl = bf16_rn(ux - bf16_tof(xh));
        unsigned short yl = bf16_rn(uy - bf16_tof(yh));
        unsigned short zl = bf16_rn(uz - bf16_tof(zh));
        const short ONE = (short)0x3F80;   // bf16 1.0
        short kv[32];
#pragma unroll
        for (int i = 0; i < 32; ++i) kv[i] = 0;
        kv[0] = (short)xh; kv[1] = (short)xh; kv[2] = (short)xl;
        kv[3] = (short)yh; kv[4] = (short)yh; kv[5] = (short)yl;
        kv[6] = (short)zh; kv[7] = (short)zh; kv[8] = (short)zl;
        kv[9] = ONE; kv[10] = ONE; kv[11] = ONE;
        int qt = qidx >> 4, m = qidx & 15;
#pragma unroll
        for (int quad = 0; quad < 4; ++quad) {
            short8 c;
#pragma unroll
            for (int j = 0; j < 8; ++j) c[j] = kv[quad * 8 + j];
            Abuf[qt * 64 + quad * 16 + m] = c;
        }
    }
}

// ---------------------------------------------------------------------------
// Kernel 2: MFMA NN scan. Grid (S=200, QG=4) = 800 blocks x 4 waves.
// Wave holds 16 qtile A-frags (64 VGPR) + 16 f4 running mins (64 VGPR);
// streams the segment's 32 mean tiles (1 coalesced dwordx4/lane/tile,
// prefetched 1 ahead). Per tile: 16 MFMA + 64 v_min_f32.
// C/D layout: col(mean)=lane&15, row(query)=(lane>>4)*4+reg  [m89/m91].
// Epilogue: xor-shuffle min over the 16 col-lanes, 4 lanes store row mins.
// ---------------------------------------------------------------------------
__global__ __launch_bounds__(256, 3) void nn_kernel(
    const short8* __restrict__ Abuf, const short8* __restrict__ Bbuf,
    float* __restrict__ partial)     // [S][P]
{
    const int t = threadIdx.x, lane = t & 63, wave = t >> 6;
    const int s  = blockIdx.x;
    const int qg = blockIdx.y;
    const int qt0 = qg * 64 + wave * 16;

    short8 a[QTW];
    f4 mn[QTW];
    const f4 zero = {0.0f, 0.0f, 0.0f, 0.0f};
#pragma unroll
    for (int i = 0; i < QTW; ++i) {
        a[i] = Abuf[(qt0 + i) * 64 + lane];
        mn[i] = (f4){1e30f, 1e30f, 1e30f, 1e30f};
    }

    const short8* bp = Bbuf + (s * TPS) * 64 + lane;
    short8 bcur = bp[0];
    for (int mt = 0; mt < TPS; ++mt) {
        short8 bnext = bp[(mt + 1) * 64];   // slack tile makes last read safe
#pragma unroll
        for (int i = 0; i < QTW; ++i) {
            f4 c = __builtin_amdgcn_mfma_f32_16x16x32_bf16(a[i], bcur, zero, 0, 0, 0);
            mn[i] = __builtin_elementwise_min(mn[i], c);
        }
        bcur = bnext;
    }

    // min across the 16 lanes sharing a quad (different mean columns)
#pragma unroll
    for (int i = 0; i < QTW; ++i) {
#pragma unroll
        for (int msk = 1; msk < 16; msk <<= 1) {
            f4 o;
#pragma unroll
            for (int c = 0; c < 4; ++c) o[c] = __shfl_xor(mn[i][c], msk, 64);
            mn[i] = __builtin_elementwise_min(mn[i], o);
        }
    }

    if ((lane & 15) == 0) {
        const int quad = lane >> 4;
#pragma unroll
        for (int i = 0; i < QTW; ++i) {
            int row = (qt0 + i) * 16 + quad * 4;
            float* dst = partial + (size_t)s * P + row;
            dst[0] = mn[i][0]; dst[1] = mn[i][1];
            dst[2] = mn[i][2]; dst[3] = mn[i][3];
        }
    }
}

// ---------------------------------------------------------------------------
// Kernel 3: final reduce. 16 blocks x 256 thr; thread q: min over 200
// segments (coalesced), d2 = clamp(qq+min,0), relu(MARGIN-d2)/P, block sum,
// atomicAdd into out.
// ---------------------------------------------------------------------------
__global__ __launch_bounds__(256) void reduce_kernel(
    const float* __restrict__ partial, const float* __restrict__ qq,
    float* __restrict__ out)
{
    const int t = threadIdx.x;
    const int q = blockIdx.x * 256 + t;

    float m = 1e30f;
#pragma unroll 8
    for (int s = 0; s < S; ++s)
        m = fminf(m, partial[s * P + q]);

    float d2 = fmaxf(qq[q] + m, 0.0f);
    float v = fmaxf(MARGIN - d2, 0.0f) * (1.0f / (float)P);

#pragma unroll
    for (int off = 32; off > 0; off >>= 1)
        v += __shfl_down(v, off, 64);

    __shared__ float lds[4];
    int wid = t >> 6;
    if ((t & 63) == 0) lds[wid] = v;
    __syncthreads();
    if (t == 0)
        atomicAdd(out, lds[0] + lds[1] + lds[2] + lds[3]);
}

extern "C" void kernel_launch(void* const* d_in, const int* in_sizes, int n_in,
                              void* d_out, int out_size, void* d_ws, size_t ws_size,
                              hipStream_t stream) {
    const float* outputs = (const float*)d_in[0];  // (64,64,3)
    const float* c2ws    = (const float*)d_in[1];  // (64,4,4)
    const float* scales  = (const float*)d_in[2];  // (64,)
    const float* means   = (const float*)d_in[3];  // (100000,3)

    char* ws = (char*)d_ws;
    short8* Abuf   = (short8*)(ws + WS_A_OFF);
    short8* Bbuf   = (short8*)(ws + WS_B_OFF);
    float*  qq     = (float*)(ws + WS_QQ_OFF);
    float*  partial= (float*)(ws + WS_PART_OFF);
    float*  out    = (float*)d_out;

    prep_kernel<<<(MPAD + P + 255) / 256, 256, 0, stream>>>(
        outputs, c2ws, scales, means, Abuf, Bbuf, qq, out);
    nn_kernel<<<dim3(S, QG), 256, 0, stream>>>(Abuf, Bbuf, partial);
    reduce_kernel<<<16, 256, 0, stream>>>(partial, qq, out);
}

// Round 8
// 121.733 us; speedup vs baseline: 1.3351x; 1.3351x over previous
//
#include <hip/hip_runtime.h>
#include <hip/hip_bf16.h>

#define MARGIN 0.0625f

// Problem sizes
#define P 4096            // queries (64*64)
#define M 100000          // means
#define MT 6400           // mean tiles of 16 (padded: 6400*16 = 102400)
#define MTA (MT + 2)      // +2 slack tiles so the 2-ahead prefetch stays in-bounds
#define MPAD (MTA * 16)   // 102432 mean slots filled by prep
#define S 200             // mean segments (nn grid.x)
#define TPS (MT / S)      // 32 tiles per segment
#define QG 8              // query groups (nn grid.y); 32 qtiles each
#define QTW 8             // qtiles per wave (4 waves * 8 * 16 = 512 q/block)

using short8 = __attribute__((ext_vector_type(8))) short;
using f4     = __attribute__((ext_vector_type(4))) float;

// ws layout (bytes):
//   Abuf : 256 qt * 64 lanes * 16 B = 262,144             @ 0
//   Bbuf : 6402 mt * 64 lanes * 16 B = 6,555,648          @ 262,144
//   qq   : 4096 * 4 = 16,384                              @ 6,817,792
//   part : 200 * 4096 * 4 = 3,276,800                     @ 6,834,176
#define WS_A_OFF    0
#define WS_B_OFF    262144
#define WS_QQ_OFF   6817792
#define WS_PART_OFF 6834176

__device__ inline unsigned short bf16_rn(float x) {
    unsigned u = __float_as_uint(x);
    return (unsigned short)((u + 0x7FFFu + ((u >> 16) & 1u)) >> 16);
}
__device__ inline float bf16_tof(unsigned short h) {
    return __uint_as_float(((unsigned)h) << 16);
}

// ---------------------------------------------------------------------------
// Kernel 1: build MFMA fragments (identical math to R7).
//  Mean j -> B k-slots: [vxh vxl vxh | vyh vyl vyh | vzh vzl vzh | mm1 mm2 mm3]
//  Query  -> A k-slots: [uxh uxh uxl | uyh uyh uyl | uzh uzh uzl | 1 1 1]
//  (u = -2q)  =>  sum_k A*B = mm - 2 q.m   (error ~1e-5 << 9.7e-4 threshold)
// ---------------------------------------------------------------------------
__global__ __launch_bounds__(256) void prep_kernel(
    const float* __restrict__ outputs, const float* __restrict__ c2ws,
    const float* __restrict__ scales,  const float* __restrict__ means,
    short8* __restrict__ Abuf, short8* __restrict__ Bbuf,
    float* __restrict__ qq, float* __restrict__ out)
{
    int idx = blockIdx.x * 256 + threadIdx.x;
    if (idx == 0) out[0] = 0.0f;   // reduce atomicAdds later (stream-ordered)

    if (idx < MPAD) {              // ---- mean side ----
        short kv[32];
#pragma unroll
        for (int i = 0; i < 32; ++i) kv[i] = 0;
        if (idx < M) {
            float x = means[3 * idx], y = means[3 * idx + 1], z = means[3 * idx + 2];
            float mm = fmaf(x, x, fmaf(y, y, z * z));
            unsigned short xh = bf16_rn(x), yh = bf16_rn(y), zh = bf16_rn(z);
            unsigned short xl = bf16_rn(x - bf16_tof(xh));
            unsigned short yl = bf16_rn(y - bf16_tof(yh));
            unsigned short zl = bf16_rn(z - bf16_tof(zh));
            unsigned short m1 = bf16_rn(mm);
            float r1 = mm - bf16_tof(m1);
            unsigned short m2 = bf16_rn(r1);
            unsigned short m3 = bf16_rn(r1 - bf16_tof(m2));
            kv[0] = (short)xh; kv[1] = (short)xl; kv[2] = (short)xh;
            kv[3] = (short)yh; kv[4] = (short)yl; kv[5] = (short)yh;
            kv[6] = (short)zh; kv[7] = (short)zl; kv[8] = (short)zh;
            kv[9] = (short)m1; kv[10] = (short)m2; kv[11] = (short)m3;
        } else {
            kv[9] = (short)bf16_rn(1e30f);   // pad mean: e = 1e30, never wins min
        }
        int mt = idx >> 4, n = idx & 15;
#pragma unroll
        for (int quad = 0; quad < 4; ++quad) {
            short8 c;
#pragma unroll
            for (int j = 0; j < 8; ++j) c[j] = kv[quad * 8 + j];
            Bbuf[mt * 64 + quad * 16 + n] = c;
        }
    }

    int qidx = idx - MPAD;         // ---- query side ----
    if (qidx >= 0 && qidx < P) {
        int b = qidx >> 6;
        float s  = scales[b];
        float o0 = outputs[3 * qidx + 0];
        float o1 = outputs[3 * qidx + 1];
        float o2 = outputs[3 * qidx + 2];
        const float* cw = c2ws + b * 16;
        float q0 = fmaf(s, fmaf(cw[0],  o0, fmaf(cw[1],  o1, cw[2]  * o2)), cw[3]);
        float q1 = fmaf(s, fmaf(cw[4],  o0, fmaf(cw[5],  o1, cw[6]  * o2)), cw[7]);
        float q2 = fmaf(s, fmaf(cw[8],  o0, fmaf(cw[9],  o1, cw[10] * o2)), cw[11]);
        qq[qidx] = fmaf(q0, q0, fmaf(q1, q1, q2 * q2));
        float ux = -2.0f * q0, uy = -2.0f * q1, uz = -2.0f * q2;
        unsigned short xh = bf16_rn(ux), yh = bf16_rn(uy), zh = bf16_rn(uz);
        unsigned short xl = bf16_rn(ux - bf16_tof(xh));
        unsigned short yl = bf16_rn(uy - bf16_tof(yh));
        unsigned short zl = bf16_rn(uz - bf16_tof(zh));
        const short ONE = (short)0x3F80;   // bf16 1.0
        short kv[32];
#pragma unroll
        for (int i = 0; i < 32; ++i) kv[i] = 0;
        kv[0] = (short)xh; kv[1] = (short)xh; kv[2] = (short)xl;
        kv[3] = (short)yh; kv[4] = (short)yh; kv[5] = (short)yl;
        kv[6] = (short)zh; kv[7] = (short)zh; kv[8] = (short)zl;
        kv[9] = ONE; kv[10] = ONE; kv[11] = ONE;
        int qt = qidx >> 4, m = qidx & 15;
#pragma unroll
        for (int quad = 0; quad < 4; ++quad) {
            short8 c;
#pragma unroll
            for (int j = 0; j < 8; ++j) c[j] = kv[quad * 8 + j];
            Abuf[qt * 64 + quad * 16 + m] = c;
        }
    }
}

// ---------------------------------------------------------------------------
// Kernel 2: MFMA NN scan. Grid (S=200, QG=8) = 1600 blocks x 4 waves.
// Wave holds 8 qtile A-frags (32 VGPR) + 8 f4 running mins (32 VGPR);
// streams the segment's 32 mean tiles two at a time (prefetch 2 ahead).
// Per tile pair: 16 MFMA + 32 v_min3_f32 (min(mn, min(c0,c1)) folds).
// Low pressure (~100 VGPR) + __launch_bounds__(256,4) keeps the min
// accumulators in ArchVGPRs -- no v_accvgpr round-trips (R7's 10x tax).
// C/D layout: col(mean)=lane&15, row(query)=(lane>>4)*4+reg  [m89/m91].
// ---------------------------------------------------------------------------
__global__ __launch_bounds__(256, 4) void nn_kernel(
    const short8* __restrict__ Abuf, const short8* __restrict__ Bbuf,
    float* __restrict__ partial)     // [S][P]
{
    const int t = threadIdx.x, lane = t & 63, wave = t >> 6;
    const int s  = blockIdx.x;
    const int qg = blockIdx.y;
    const int qt0 = qg * 32 + wave * 8;

    short8 a[QTW];
    f4 mn[QTW];
    const f4 zero = {0.0f, 0.0f, 0.0f, 0.0f};
#pragma unroll
    for (int i = 0; i < QTW; ++i) {
        a[i] = Abuf[(qt0 + i) * 64 + lane];
        mn[i] = (f4){1e30f, 1e30f, 1e30f, 1e30f};
    }

    const short8* bp = Bbuf + (s * TPS) * 64 + lane;
    short8 b0 = bp[0];
    short8 b1 = bp[64];
    for (int mt = 0; mt < TPS; mt += 2) {
        short8 n0 = bp[(mt + 2) * 64];   // slack tiles make the last read safe
        short8 n1 = bp[(mt + 3) * 64];
#pragma unroll
        for (int i = 0; i < QTW; ++i) {
            f4 c0 = __builtin_amdgcn_mfma_f32_16x16x32_bf16(a[i], b0, zero, 0, 0, 0);
            f4 c1 = __builtin_amdgcn_mfma_f32_16x16x32_bf16(a[i], b1, zero, 0, 0, 0);
            mn[i] = __builtin_elementwise_min(mn[i],
                    __builtin_elementwise_min(c0, c1));   // v_min3_f32
        }
        b0 = n0; b1 = n1;
    }

    // min across the 16 lanes sharing a quad (different mean columns)
#pragma unroll
    for (int i = 0; i < QTW; ++i) {
#pragma unroll
        for (int msk = 1; msk < 16; msk <<= 1) {
            f4 o;
#pragma unroll
            for (int c = 0; c < 4; ++c) o[c] = __shfl_xor(mn[i][c], msk, 64);
            mn[i] = __builtin_elementwise_min(mn[i], o);
        }
    }

    if ((lane & 15) == 0) {
        const int quad = lane >> 4;
#pragma unroll
        for (int i = 0; i < QTW; ++i) {
            int row = (qt0 + i) * 16 + quad * 4;
            float* dst = partial + (size_t)s * P + row;
            dst[0] = mn[i][0]; dst[1] = mn[i][1];
            dst[2] = mn[i][2]; dst[3] = mn[i][3];
        }
    }
}

// ---------------------------------------------------------------------------
// Kernel 3: final reduce. 16 blocks x 256 thr; thread q: min over 200
// segments (coalesced), d2 = clamp(qq+min,0), relu(MARGIN-d2)/P, block sum,
// atomicAdd into out.
// ---------------------------------------------------------------------------
__global__ __launch_bounds__(256) void reduce_kernel(
    const float* __restrict__ partial, const float* __restrict__ qq,
    float* __restrict__ out)
{
    const int t = threadIdx.x;
    const int q = blockIdx.x * 256 + t;

    float m = 1e30f;
#pragma unroll 8
    for (int s = 0; s < S; ++s)
        m = fminf(m, partial[s * P + q]);

    float d2 = fmaxf(qq[q] + m, 0.0f);
    float v = fmaxf(MARGIN - d2, 0.0f) * (1.0f / (float)P);

#pragma unroll
    for (int off = 32; off > 0; off >>= 1)
        v += __shfl_down(v, off, 64);

    __shared__ float lds[4];
    int wid = t >> 6;
    if ((t & 63) == 0) lds[wid] = v;
    __syncthreads();
    if (t == 0)
        atomicAdd(out, lds[0] + lds[1] + lds[2] + lds[3]);
}

extern "C" void kernel_launch(void* const* d_in, const int* in_sizes, int n_in,
                              void* d_out, int out_size, void* d_ws, size_t ws_size,
                              hipStream_t stream) {
    const float* outputs = (const float*)d_in[0];  // (64,64,3)
    const float* c2ws    = (const float*)d_in[1];  // (64,4,4)
    const float* scales  = (const float*)d_in[2];  // (64,)
    const float* means   = (const float*)d_in[3];  // (100000,3)

    char* ws = (char*)d_ws;
    short8* Abuf    = (short8*)(ws + WS_A_OFF);
    short8* Bbuf    = (short8*)(ws + WS_B_OFF);
    float*  qq      = (float*)(ws + WS_QQ_OFF);
    float*  partial = (float*)(ws + WS_PART_OFF);
    float*  out     = (float*)d_out;

    prep_kernel<<<(MPAD + P + 255) / 256, 256, 0, stream>>>(
        outputs, c2ws, scales, means, Abuf, Bbuf, qq, out);
    nn_kernel<<<dim3(S, QG), 256, 0, stream>>>(Abuf, Bbuf, partial);
    reduce_kernel<<<16, 256, 0, stream>>>(partial, qq, out);
}

// Round 9
// 118.269 us; speedup vs baseline: 1.3742x; 1.0293x over previous
//
#include <hip/hip_runtime.h>
#include <hip/hip_bf16.h>

#define MARGIN 0.0625f

// Problem sizes
#define P 4096            // queries (64*64)
#define M 100000          // means
#define MT 6400           // mean tiles of 16 (6400*16 = 102400 padded slots)
#define MTA (MT + 2)      // +2 slack tiles for the 2-ahead prefetch
#define MPAD (MTA * 16)   // 102432 mean slots written by prep
#define S 200             // mean segments (nn grid.x)
#define TPS (MT / S)      // 32 tiles per segment
#define QG 8              // query groups (nn grid.y)
#define QTW 8             // qtiles per wave (4 waves * 8 * 16 = 512 q/block)

using u2v = __attribute__((ext_vector_type(2))) unsigned int;  // 2 dwords = 4 bf16
using f4  = __attribute__((ext_vector_type(4))) float;

// ws layout (bytes):
//   Abuf : 256 qt * 64 lanes * 8 B  =   131,072   @ 0
//   Bbuf : 6402 mt * 64 lanes * 8 B = 3,277,824   @ 131,072
//   qq   : 4096 * 4                 =    16,384   @ 3,408,896
//   part : 200 * 4096 * 4           = 3,276,800   @ 3,425,280
#define WS_A_OFF    0
#define WS_B_OFF    131072
#define WS_QQ_OFF   3408896
#define WS_PART_OFF 3425280

__device__ inline unsigned bf16_rn(float x) {
    unsigned u = __float_as_uint(x);
    return (u + 0x7FFFu + ((u >> 16) & 1u)) >> 16;
}
__device__ inline float bf16_tof(unsigned h) {
    return __uint_as_float(h << 16);
}

// ---------------------------------------------------------------------------
// Kernel 1: build 16x16x16-bf16 MFMA fragments.
// K-slot encoding (u = -2q, v = mean, 2-way splits + 3-way mm split):
//   A k-vec: [uxh uxh uxl uyh | uyh uyl uzh uzh | uzl 1 1 1 | 0 0 0 0]
//   B k-vec: [vxh vxl vxh vyh | vyl vyh vzh vzl | vzh m1 m2 m3 | 0 0 0 0]
//   sum_k A*B = |m|^2 - 2 q.m   (same math as R7/R8: absmax was 0.0)
// Fragment layout: lane = quad*16 + (row|col), reg j holds k = quad*4 + j,
// two bf16 per dword (low = even j).
// ---------------------------------------------------------------------------
__global__ __launch_bounds__(256) void prep_kernel(
    const float* __restrict__ outputs, const float* __restrict__ c2ws,
    const float* __restrict__ scales,  const float* __restrict__ means,
    u2v* __restrict__ Abuf, u2v* __restrict__ Bbuf,
    float* __restrict__ qq, float* __restrict__ out)
{
    int idx = blockIdx.x * 256 + threadIdx.x;
    if (idx == 0) out[0] = 0.0f;   // reduce atomicAdds later (stream-ordered)

    if (idx < MPAD) {              // ---- mean side ----
        float x = 0.0f, y = 0.0f, z = 0.0f, mm = 1e30f;  // pad: e = 1e30
        if (idx < M) {
            x = means[3 * idx]; y = means[3 * idx + 1]; z = means[3 * idx + 2];
            mm = fmaf(x, x, fmaf(y, y, z * z));
        }
        unsigned xh = bf16_rn(x), yh = bf16_rn(y), zh = bf16_rn(z);
        unsigned xl = bf16_rn(x - bf16_tof(xh));
        unsigned yl = bf16_rn(y - bf16_tof(yh));
        unsigned zl = bf16_rn(z - bf16_tof(zh));
        unsigned m1 = bf16_rn(mm);
        float   r1 = mm - bf16_tof(m1);
        unsigned m2 = bf16_rn(r1);
        unsigned m3 = bf16_rn(r1 - bf16_tof(m2));

        int mt = idx >> 4, n = idx & 15;
        u2v* dst = Bbuf + mt * 64 + n;
        dst[0]  = (u2v){xh | (xl << 16), xh | (yh << 16)};
        dst[16] = (u2v){yl | (yh << 16), zh | (zl << 16)};
        dst[32] = (u2v){zh | (m1 << 16), m2 | (m3 << 16)};
        dst[48] = (u2v){0u, 0u};
        return;
    }

    int qidx = idx - MPAD;         // ---- query side ----
    if (qidx < P) {
        int b = qidx >> 6;
        float s  = scales[b];
        float o0 = outputs[3 * qidx + 0];
        float o1 = outputs[3 * qidx + 1];
        float o2 = outputs[3 * qidx + 2];
        const float* cw = c2ws + b * 16;
        float q0 = fmaf(s, fmaf(cw[0],  o0, fmaf(cw[1],  o1, cw[2]  * o2)), cw[3]);
        float q1 = fmaf(s, fmaf(cw[4],  o0, fmaf(cw[5],  o1, cw[6]  * o2)), cw[7]);
        float q2 = fmaf(s, fmaf(cw[8],  o0, fmaf(cw[9],  o1, cw[10] * o2)), cw[11]);
        qq[qidx] = fmaf(q0, q0, fmaf(q1, q1, q2 * q2));
        float ux = -2.0f * q0, uy = -2.0f * q1, uz = -2.0f * q2;
        unsigned xh = bf16_rn(ux), yh = bf16_rn(uy), zh = bf16_rn(uz);
        unsigned xl = bf16_rn(ux - bf16_tof(xh));
        unsigned yl = bf16_rn(uy - bf16_tof(yh));
        unsigned zl = bf16_rn(uz - bf16_tof(zh));
        const unsigned ONE = 0x3F80u;   // bf16 1.0

        int qt = qidx >> 4, m = qidx & 15;
        u2v* dst = Abuf + qt * 64 + m;
        dst[0]  = (u2v){xh | (xh << 16), xl | (yh << 16)};
        dst[16] = (u2v){yh | (yl << 16), zh | (zh << 16)};
        dst[32] = (u2v){zl | (ONE << 16), ONE | (ONE << 16)};
        dst[48] = (u2v){0u, 0u};
    }
}

// ---- inline-asm MFMA: "=&v" forces ArchVGPR results (no AGPR round-trip).
// 4 MFMAs per block: qtile pair (a0,a1) x mean-tile pair (b0,b1).
__device__ inline void mfma4(f4& c0, f4& c1, f4& c2, f4& c3,
                             u2v a0, u2v a1, u2v b0, u2v b1) {
    asm volatile(
        "v_mfma_f32_16x16x16_bf16 %0, %4, %6, 0\n\t"
        "v_mfma_f32_16x16x16_bf16 %1, %4, %7, 0\n\t"
        "v_mfma_f32_16x16x16_bf16 %2, %5, %6, 0\n\t"
        "v_mfma_f32_16x16x16_bf16 %3, %5, %7, 0"
        : "=&v"(c0), "=&v"(c1), "=&v"(c2), "=&v"(c3)
        : "v"(a0), "v"(a1), "v"(b0), "v"(b1));
}

// volatile v_min3 fold: ordered against the MFMA asm blocks, so the
// scheduler cannot shrink the MFMA->VALU-read gap below the source order.
__device__ inline void fold2(f4& mn, const f4& c0, const f4& c1) {
#pragma unroll
    for (int c = 0; c < 4; ++c) {
        float m = mn[c];
        asm volatile("v_min3_f32 %0, %1, %2, %0"
                     : "+v"(m) : "v"(c0[c]), "v"(c1[c]));
        mn[c] = m;
    }
}

// ---------------------------------------------------------------------------
// Kernel 2: MFMA NN scan. Grid (S=200, QG=8) = 1600 blocks x 4 waves.
// Wave: 8 qtile A-frags (16 VGPR) + 8 f4 mins (32 VGPR); streams 32 mean
// tiles in pairs (prefetch 2 ahead). Pipeline: issue MFMAs for qtile-pair k,
// fold pair k-1 -> >=8-16 cyc MFMA->read spacing (hazard-safe).
// C/D layout: col(mean)=lane&15, row(query)=(lane>>4)*4+reg.
// ---------------------------------------------------------------------------
__global__ __launch_bounds__(256, 4) void nn_kernel(
    const u2v* __restrict__ Abuf, const u2v* __restrict__ Bbuf,
    float* __restrict__ partial)     // [S][P]
{
    const int t = threadIdx.x, lane = t & 63, wave = t >> 6;
    const int s  = blockIdx.x;
    const int qg = blockIdx.y;
    const int qt0 = qg * 32 + wave * 8;

    u2v a[QTW];
    f4 mn[QTW];
#pragma unroll
    for (int i = 0; i < QTW; ++i) {
        a[i] = Abuf[(qt0 + i) * 64 + lane];
        mn[i] = (f4){1e30f, 1e30f, 1e30f, 1e30f};
    }

    const u2v* bp = Bbuf + (s * TPS) * 64 + lane;
    u2v b0 = bp[0];
    u2v b1 = bp[64];
    f4 cA0, cA1, cA2, cA3, cB0, cB1, cB2, cB3;

    for (int mt = 0; mt < TPS; mt += 2) {
        u2v n0 = bp[(mt + 2) * 64];   // slack tiles keep this in-bounds
        u2v n1 = bp[(mt + 3) * 64];
        mfma4(cA0, cA1, cA2, cA3, a[0], a[1], b0, b1);
        mfma4(cB0, cB1, cB2, cB3, a[2], a[3], b0, b1);
        fold2(mn[0], cA0, cA1); fold2(mn[1], cA2, cA3);
        mfma4(cA0, cA1, cA2, cA3, a[4], a[5], b0, b1);
        fold2(mn[2], cB0, cB1); fold2(mn[3], cB2, cB3);
        mfma4(cB0, cB1, cB2, cB3, a[6], a[7], b0, b1);
        fold2(mn[4], cA0, cA1); fold2(mn[5], cA2, cA3);
        fold2(mn[6], cB0, cB1); fold2(mn[7], cB2, cB3);
        b0 = n0; b1 = n1;
    }

    // min across the 16 lanes of each quad (16 mean columns)
#pragma unroll
    for (int i = 0; i < QTW; ++i) {
#pragma unroll
        for (int msk = 1; msk < 16; msk <<= 1) {
            f4 o;
#pragma unroll
            for (int c = 0; c < 4; ++c) o[c] = __shfl_xor(mn[i][c], msk, 64);
            mn[i] = __builtin_elementwise_min(mn[i], o);
        }
    }

    if ((lane & 15) == 0) {
        const int quad = lane >> 4;
#pragma unroll
        for (int i = 0; i < QTW; ++i) {
            int row = (qt0 + i) * 16 + quad * 4;
            float* dst = partial + (size_t)s * P + row;
            dst[0] = mn[i][0]; dst[1] = mn[i][1];
            dst[2] = mn[i][2]; dst[3] = mn[i][3];
        }
    }
}

// ---------------------------------------------------------------------------
// Kernel 3: final reduce. 16 blocks x 256 thr; thread q: min over 200
// segments (coalesced, L2-hot), d2 = clamp(qq+min,0), relu(MARGIN-d2)/P,
// block sum, atomicAdd into out.
// ---------------------------------------------------------------------------
__global__ __launch_bounds__(256) void reduce_kernel(
    const float* __restrict__ partial, const float* __restrict__ qq,
    float* __restrict__ out)
{
    const int t = threadIdx.x;
    const int q = blockIdx.x * 256 + t;

    float m = 1e30f;
#pragma unroll 8
    for (int s = 0; s < S; ++s)
        m = fminf(m, partial[s * P + q]);

    float d2 = fmaxf(qq[q] + m, 0.0f);
    float v = fmaxf(MARGIN - d2, 0.0f) * (1.0f / (float)P);

#pragma unroll
    for (int off = 32; off > 0; off >>= 1)
        v += __shfl_down(v, off, 64);

    __shared__ float lds[4];
    int wid = t >> 6;
    if ((t & 63) == 0) lds[wid] = v;
    __syncthreads();
    if (t == 0)
        atomicAdd(out, lds[0] + lds[1] + lds[2] + lds[3]);
}

extern "C" void kernel_launch(void* const* d_in, const int* in_sizes, int n_in,
                              void* d_out, int out_size, void* d_ws, size_t ws_size,
                              hipStream_t stream) {
    const float* outputs = (const float*)d_in[0];  // (64,64,3)
    const float* c2ws    = (const float*)d_in[1];  // (64,4,4)
    const float* scales  = (const float*)d_in[2];  // (64,)
    const float* means   = (const float*)d_in[3];  // (100000,3)

    char* ws = (char*)d_ws;
    u2v*   Abuf    = (u2v*)(ws + WS_A_OFF);
    u2v*   Bbuf    = (u2v*)(ws + WS_B_OFF);
    float* qq      = (float*)(ws + WS_QQ_OFF);
    float* partial = (float*)(ws + WS_PART_OFF);
    float* out     = (float*)d_out;

    prep_kernel<<<(MPAD + P + 255) / 256, 256, 0, stream>>>(
        outputs, c2ws, scales, means, Abuf, Bbuf, qq, out);
    nn_kernel<<<dim3(S, QG), 256, 0, stream>>>(Abuf, Bbuf, partial);
    reduce_kernel<<<16, 256, 0, stream>>>(partial, qq, out);
}

// Round 10
// 106.832 us; speedup vs baseline: 1.5213x; 1.1071x over previous
//
#include <hip/hip_runtime.h>
#include <hip/hip_bf16.h>

#define MARGIN 0.0625f

// Problem sizes
#define P 4096            // queries (64*64)
#define M 100000          // means
#define S 200             // mean segments (nn grid.x); 512 means each
#define SEGM 512          // means per segment (= 32 tiles of 16)
#define MPAD (S * SEGM)   // 102400 padded mean slots (pads get |m|^2 = 1e30)
#define QG 8              // query groups (nn grid.y)
#define QTW 8             // qtiles per wave (4 waves * 8 * 16 = 512 q/block)
#define NPAIRS 16         // 32 tiles per segment processed as 16 pairs

using u2v = __attribute__((ext_vector_type(2))) unsigned int;  // 8 B
using u4v = __attribute__((ext_vector_type(4))) unsigned int;  // 16 B
using f4  = __attribute__((ext_vector_type(4))) float;

// ws layout (bytes):
//   Abuf : 256 qt * 64 lanes * 8 B = 131,072    @ 0
//   Bbuf : 200 seg * 16 KB        = 3,276,800   @ 131,072
//   qq   : 4096 * 4               = 16,384      @ 3,407,872
//   qmin : 4096 * 4 (uint keys)   = 16,384      @ 3,424,256
#define WS_A_OFF    0
#define WS_B_OFF    131072
#define WS_QQ_OFF   3407872
#define WS_QMIN_OFF 3424256

__device__ inline unsigned bf16_rn(float x) {
    unsigned u = __float_as_uint(x);
    return (u + 0x7FFFu + ((u >> 16) & 1u)) >> 16;
}
__device__ inline float bf16_tof(unsigned h) { return __uint_as_float(h << 16); }

// order-preserving float -> uint key (for atomicMin over possibly-negative d')
__device__ inline unsigned fkey(float f) {
    unsigned u = __float_as_uint(f);
    return (u >> 31) ? ~u : (u | 0x80000000u);
}

// ---------------------------------------------------------------------------
// Kernel 1: build 16x16x16-bf16 MFMA fragments (K-encoding identical to R9,
// absmax 0.0 verified).  B is stored pair-interleaved per segment so nn can
// fetch 2 tiles with one ds_read_b128:
//   u2-index within segment = p*128 + quad*32 + n*2 + h   (tile = 2p+h, col n)
// Also inits qmin keys to 0xFFFFFFFF and zeroes out[0].
// ---------------------------------------------------------------------------
__global__ __launch_bounds__(256) void prep_kernel(
    const float* __restrict__ outputs, const float* __restrict__ c2ws,
    const float* __restrict__ scales,  const float* __restrict__ means,
    u2v* __restrict__ Abuf, u2v* __restrict__ Bbuf,
    float* __restrict__ qq, unsigned* __restrict__ qmin,
    float* __restrict__ out)
{
    int idx = blockIdx.x * 256 + threadIdx.x;
    if (idx == 0) out[0] = 0.0f;   // final kernel atomicAdds (stream-ordered)

    if (idx < MPAD) {              // ---- mean side ----
        float x = 0.0f, y = 0.0f, z = 0.0f, mm = 1e30f;  // pad: never wins min
        if (idx < M) {
            x = means[3 * idx]; y = means[3 * idx + 1]; z = means[3 * idx + 2];
            mm = fmaf(x, x, fmaf(y, y, z * z));
        }
        unsigned xh = bf16_rn(x), yh = bf16_rn(y), zh = bf16_rn(z);
        unsigned xl = bf16_rn(x - bf16_tof(xh));
        unsigned yl = bf16_rn(y - bf16_tof(yh));
        unsigned zl = bf16_rn(z - bf16_tof(zh));
        unsigned m1 = bf16_rn(mm);
        float   r1 = mm - bf16_tof(m1);
        unsigned m2 = bf16_rn(r1);
        unsigned m3 = bf16_rn(r1 - bf16_tof(m2));

        int s = idx >> 9, w = idx & 511;
        int tt = w >> 4, n = w & 15, p = tt >> 1, h = tt & 1;
        u2v* dst = Bbuf + s * 2048 + p * 128 + n * 2 + h;   // quad stride 32
        dst[0]  = (u2v){xh | (xl << 16), xh | (yh << 16)};
        dst[32] = (u2v){yl | (yh << 16), zh | (zl << 16)};
        dst[64] = (u2v){zh | (m1 << 16), m2 | (m3 << 16)};
        dst[96] = (u2v){0u, 0u};
        return;
    }

    int qidx = idx - MPAD;         // ---- query side ----
    if (qidx < P) {
        qmin[qidx] = 0xFFFFFFFFu;
        int b = qidx >> 6;
        float s  = scales[b];
        float o0 = outputs[3 * qidx + 0];
        float o1 = outputs[3 * qidx + 1];
        float o2 = outputs[3 * qidx + 2];
        const float* cw = c2ws + b * 16;
        float q0 = fmaf(s, fmaf(cw[0],  o0, fmaf(cw[1],  o1, cw[2]  * o2)), cw[3]);
        float q1 = fmaf(s, fmaf(cw[4],  o0, fmaf(cw[5],  o1, cw[6]  * o2)), cw[7]);
        float q2 = fmaf(s, fmaf(cw[8],  o0, fmaf(cw[9],  o1, cw[10] * o2)), cw[11]);
        qq[qidx] = fmaf(q0, q0, fmaf(q1, q1, q2 * q2));
        float ux = -2.0f * q0, uy = -2.0f * q1, uz = -2.0f * q2;
        unsigned xh = bf16_rn(ux), yh = bf16_rn(uy), zh = bf16_rn(uz);
        unsigned xl = bf16_rn(ux - bf16_tof(xh));
        unsigned yl = bf16_rn(uy - bf16_tof(yh));
        unsigned zl = bf16_rn(uz - bf16_tof(zh));
        const unsigned ONE = 0x3F80u;   // bf16 1.0
        int qt = qidx >> 4, m = qidx & 15;
        u2v* dst = Abuf + qt * 64 + m;
        dst[0]  = (u2v){xh | (xh << 16), xl | (yh << 16)};
        dst[16] = (u2v){yh | (yl << 16), zh | (zh << 16)};
        dst[32] = (u2v){zl | (ONE << 16), ONE | (ONE << 16)};
        dst[48] = (u2v){0u, 0u};
    }
}

// ---- inline-asm MFMA: "=&v" forces ArchVGPR results (no AGPR round-trip).
__device__ inline void mfma4(f4& c0, f4& c1, f4& c2, f4& c3,
                             u2v a0, u2v a1, u2v b0, u2v b1) {
    asm volatile(
        "v_mfma_f32_16x16x16_bf16 %0, %4, %6, 0\n\t"
        "v_mfma_f32_16x16x16_bf16 %1, %4, %7, 0\n\t"
        "v_mfma_f32_16x16x16_bf16 %2, %5, %6, 0\n\t"
        "v_mfma_f32_16x16x16_bf16 %3, %5, %7, 0"
        : "=&v"(c0), "=&v"(c1), "=&v"(c2), "=&v"(c3)
        : "v"(a0), "v"(a1), "v"(b0), "v"(b1));
}
__device__ inline void fold2(f4& mn, const f4& c0, const f4& c1) {
#pragma unroll
    for (int c = 0; c < 4; ++c) {
        float m = mn[c];
        asm volatile("v_min3_f32 %0, %1, %2, %0"
                     : "+v"(m) : "v"(c0[c]), "v"(c1[c]));
        mn[c] = m;
    }
}

// ---------------------------------------------------------------------------
// Kernel 2: MFMA NN scan, LDS-staged B (no global access in the K-loop).
// Grid (S=200, QG=8) = 1600 blocks x 4 waves. Block: copy its segment's
// 16 KB of B into LDS (coalesced, once), barrier, then 16 pair-iterations:
// 1 ds_read_b128 (2 tiles) + 16 MFMA + 32 v_min3 per wave.  Epilogue:
// 16-lane xor-min then atomicMin(qmin[row], key) -- no partial buffer.
// ---------------------------------------------------------------------------
__global__ __launch_bounds__(256, 4) void nn_kernel(
    const u2v* __restrict__ Abuf, const u2v* __restrict__ Bbuf,
    unsigned* __restrict__ qmin)
{
    const int t = threadIdx.x, lane = t & 63, wave = t >> 6;
    const int s  = blockIdx.x;
    const int qg = blockIdx.y;
    const int qt0 = qg * 32 + wave * 8;

    __shared__ u4v ldsB[1024];   // 16 KB: pair p at ldsB[p*64 + lane]

    // ---- stage segment B into LDS (dwordx4 global -> ds_write_b128) ----
    const u4v* src4 = (const u4v*)(Bbuf + (size_t)s * 2048);
#pragma unroll
    for (int k = 0; k < 4; ++k)
        ldsB[t + k * 256] = src4[t + k * 256];

    // ---- A fragments + min init ----
    u2v a[QTW];
    f4 mn[QTW];
#pragma unroll
    for (int i = 0; i < QTW; ++i) {
        a[i] = Abuf[(qt0 + i) * 64 + lane];
        mn[i] = (f4){1e30f, 1e30f, 1e30f, 1e30f};
    }

    __syncthreads();

    f4 cA0, cA1, cA2, cA3, cB0, cB1, cB2, cB3;
    u4v bc = ldsB[lane];                       // pair 0
    for (int p = 0; p < NPAIRS; ++p) {
        u4v bn = ldsB[(((p + 1) & 15) << 6) + lane];   // prefetch next pair
        u2v b0 = (u2v){bc[0], bc[1]};
        u2v b1 = (u2v){bc[2], bc[3]};
        mfma4(cA0, cA1, cA2, cA3, a[0], a[1], b0, b1);
        mfma4(cB0, cB1, cB2, cB3, a[2], a[3], b0, b1);
        fold2(mn[0], cA0, cA1); fold2(mn[1], cA2, cA3);
        mfma4(cA0, cA1, cA2, cA3, a[4], a[5], b0, b1);
        fold2(mn[2], cB0, cB1); fold2(mn[3], cB2, cB3);
        mfma4(cB0, cB1, cB2, cB3, a[6], a[7], b0, b1);
        fold2(mn[4], cA0, cA1); fold2(mn[5], cA2, cA3);
        fold2(mn[6], cB0, cB1); fold2(mn[7], cB2, cB3);
        bc = bn;
    }

    // ---- min across the 16 lanes of each quad (16 mean columns) ----
#pragma unroll
    for (int i = 0; i < QTW; ++i) {
#pragma unroll
        for (int msk = 1; msk < 16; msk <<= 1) {
            f4 o;
#pragma unroll
            for (int c = 0; c < 4; ++c) o[c] = __shfl_xor(mn[i][c], msk, 64);
            mn[i] = __builtin_elementwise_min(mn[i], o);
        }
    }

    if ((lane & 15) == 0) {
        const int quad = lane >> 4;
#pragma unroll
        for (int i = 0; i < QTW; ++i) {
            int row = (qt0 + i) * 16 + quad * 4;
#pragma unroll
            for (int c = 0; c < 4; ++c)
                atomicMin(&qmin[row + c], fkey(mn[i][c]));
        }
    }
}

// ---------------------------------------------------------------------------
// Kernel 3: final. 16 blocks x 256 thr; thread q: decode key, d2 =
// clamp(qq+min, 0), relu(MARGIN-d2)/P, wave+LDS sum, atomicAdd into out.
// ---------------------------------------------------------------------------
__global__ __launch_bounds__(256) void final_kernel(
    const unsigned* __restrict__ qmin, const float* __restrict__ qq,
    float* __restrict__ out)
{
    const int t = threadIdx.x;
    const int q = blockIdx.x * 256 + t;

    unsigned key = qmin[q];
    unsigned u = (key & 0x80000000u) ? (key ^ 0x80000000u) : ~key;
    float dmin = __uint_as_float(u);
    float d2 = fmaxf(qq[q] + dmin, 0.0f);
    float v = fmaxf(MARGIN - d2, 0.0f) * (1.0f / (float)P);

#pragma unroll
    for (int off = 32; off > 0; off >>= 1)
        v += __shfl_down(v, off, 64);

    __shared__ float lds[4];
    int wid = t >> 6;
    if ((t & 63) == 0) lds[wid] = v;
    __syncthreads();
    if (t == 0)
        atomicAdd(out, lds[0] + lds[1] + lds[2] + lds[3]);
}

extern "C" void kernel_launch(void* const* d_in, const int* in_sizes, int n_in,
                              void* d_out, int out_size, void* d_ws, size_t ws_size,
                              hipStream_t stream) {
    const float* outputs = (const float*)d_in[0];  // (64,64,3)
    const float* c2ws    = (const float*)d_in[1];  // (64,4,4)
    const float* scales  = (const float*)d_in[2];  // (64,)
    const float* means   = (const float*)d_in[3];  // (100000,3)

    char* ws = (char*)d_ws;
    u2v*      Abuf = (u2v*)(ws + WS_A_OFF);
    u2v*      Bbuf = (u2v*)(ws + WS_B_OFF);
    float*    qq   = (float*)(ws + WS_QQ_OFF);
    unsigned* qmin = (unsigned*)(ws + WS_QMIN_OFF);
    float*    out  = (float*)d_out;

    prep_kernel<<<(MPAD + P) / 256, 256, 0, stream>>>(
        outputs, c2ws, scales, means, Abuf, Bbuf, qq, qmin, out);
    nn_kernel<<<dim3(S, QG), 256, 0, stream>>>(Abuf, Bbuf, qmin);
    final_kernel<<<P / 256, 256, 0, stream>>>(qmin, qq, out);
}